// Round 2
// baseline (373.959 us; speedup 1.0000x reference)
//
#include <hip/hip_runtime.h>

// out[b,o,l] = sum_i x[b,i,k'(l)] * P[i,o,f'(l)],  k'=idx[l]&4095, f'=idx[l]>>12
// Phase 1a: xT[b,k,i] = bf16(x[b,i,k])          (coalesced transpose+cast, d_ws)
// Phase 1b: Pbf[f][o][i] = bf16(P[i,o,f])       (A-fragment-friendly layout, d_ws)
// Phase 2 : LDS-free gather-GEMM. B-fragments (16B/lane) loaded directly from the
//           gathered xT row; 4 accumulator sets (one per f), per-lane cndmask select.

typedef __attribute__((ext_vector_type(8))) short short8;
typedef __attribute__((ext_vector_type(4))) float floatx4;

#define NB    64
#define CIN   64
#define COUT  64
#define KDIM  4096
#define LDIM  16384
#define LT    16      // 16-wide l-tiles per block => 256 l's per block

__device__ __forceinline__ unsigned short f2bf(float f) {
  union { float f; unsigned u; } v; v.f = f;
  unsigned r = v.u + 0x7FFFu + ((v.u >> 16) & 1u);  // RNE
  return (unsigned short)(r >> 16);
}

union V16 { uint4 u; short8 s; };

__global__ __launch_bounds__(256) void transpose_bf16(const float* __restrict__ x,
                                                      unsigned short* __restrict__ xt) {
  __shared__ float tile[64 * 65];  // [i][k], +1 pad
  const int t = threadIdx.x;
  const int b = blockIdx.y;
  const int k0 = blockIdx.x * 64;
  const float4* x4 = (const float4*)x;
#pragma unroll
  for (int p = 0; p < 4; ++p) {
    int i  = p * 16 + (t >> 4);
    int kq = t & 15;
    float4 v = x4[(size_t)(b * CIN + i) * (KDIM / 4) + (k0 >> 2) + kq];
    tile[i * 65 + kq * 4 + 0] = v.x;
    tile[i * 65 + kq * 4 + 1] = v.y;
    tile[i * 65 + kq * 4 + 2] = v.z;
    tile[i * 65 + kq * 4 + 3] = v.w;
  }
  __syncthreads();
  unsigned int* xt32 = (unsigned int*)xt;
  const int ip = (t & 31) * 2;  // pair of i's packed into one u32 store
#pragma unroll
  for (int p = 0; p < 8; ++p) {
    int k = p * 8 + (t >> 5);
    unsigned lo = f2bf(tile[ip * 65 + k]);
    unsigned hi = f2bf(tile[(ip + 1) * 65 + k]);
    xt32[((size_t)b * KDIM + k0 + k) * (CIN / 2) + (ip >> 1)] = lo | (hi << 16);
  }
}

__global__ __launch_bounds__(256) void prep_params(const float* __restrict__ params,
                                                   unsigned short* __restrict__ pbf) {
  // pbf[((f*64+o)*64+i)] = bf16(params[(i*64+o)*4+f]); 16384 elems, 64 blocks
  const int e = blockIdx.x * 256 + threadIdx.x;
  const int f = e >> 12, o = (e >> 6) & 63, i = e & 63;
  pbf[e] = f2bf(params[(i * COUT + o) * 4 + f]);
}

__global__ __launch_bounds__(256) void gemm_gather(const unsigned short* __restrict__ xt,
                                                   const unsigned short* __restrict__ pbf,
                                                   const int* __restrict__ idx,
                                                   float* __restrict__ out) {
  const int t = threadIdx.x;
  const int b = blockIdx.y;
  const int w = t >> 6;          // wave id = o-tile
  const int lane = t & 63;
  const int quad = lane >> 4;
  const int lane15 = lane & 15;
  const int o = w * 16 + lane15;

  // A fragments: A[m=o][k=i], lane m=lane15, k=quad*8+j -> 16B from Pbf[f][o][.]
  short8 afrag[4][2];
#pragma unroll
  for (int f = 0; f < 4; ++f)
#pragma unroll
    for (int kt = 0; kt < 2; ++kt) {
      V16 v; v.u = *(const uint4*)(pbf + ((f * COUT + o) * CIN + kt * 32 + quad * 8));
      afrag[f][kt] = v.s;
    }

  const int lbase = blockIdx.x * (LT * 16);
  const unsigned short* xb = xt + (size_t)b * KDIM * CIN;
  const floatx4 zero = {0.f, 0.f, 0.f, 0.f};

  // software pipeline: b-frags for tile `it` loaded during tile `it-1`'s MFMAs
  int iv_cur = idx[lbase + lane15];
  int iv_nxt = idx[lbase + 16 + lane15];
  uint4 b0c, b1c;
  {
    const uint4* row = (const uint4*)(xb + (size_t)(iv_cur & (KDIM - 1)) * CIN);
    b0c = row[quad];      // kt=0: i in [quad*8, quad*8+8)
    b1c = row[4 + quad];  // kt=1: i in [32+quad*8, ...)
  }

  for (int it = 0; it < LT; ++it) {
    uint4 b0n = b0c, b1n = b1c;
    int iv_nn = iv_nxt;
    if (it + 1 < LT) {
      const uint4* row = (const uint4*)(xb + (size_t)(iv_nxt & (KDIM - 1)) * CIN);
      b0n = row[quad];
      b1n = row[4 + quad];
      int ln = lbase + (it + 2) * 16 + lane15;
      iv_nn = idx[ln < LDIM ? ln : LDIM - 1];
    }

    V16 v0, v1; v0.u = b0c; v1.u = b1c;
    floatx4 acc[4];
#pragma unroll
    for (int f = 0; f < 4; ++f) {
      acc[f] = __builtin_amdgcn_mfma_f32_16x16x32_bf16(afrag[f][0], v0.s, zero, 0, 0, 0);
      acc[f] = __builtin_amdgcn_mfma_f32_16x16x32_bf16(afrag[f][1], v1.s, acc[f], 0, 0, 0);
    }

    // select per lane: f' = iv_cur>>12 (same for all 4 regs: col=lane, rows=o)
    const int fp = iv_cur >> 12;
    const int l = lbase + it * 16 + lane15;
#pragma unroll
    for (int r = 0; r < 4; ++r) {
      float v01 = (fp == 0) ? acc[0][r] : acc[1][r];
      float v23 = (fp == 2) ? acc[2][r] : acc[3][r];
      float v = (fp < 2) ? v01 : v23;
      const int oo = w * 16 + quad * 4 + r;
      out[((size_t)(b * COUT + oo)) * LDIM + l] = v;
    }

    iv_cur = iv_nxt; iv_nxt = iv_nn;
    b0c = b0n; b1c = b1n;
  }
}

extern "C" void kernel_launch(void* const* d_in, const int* in_sizes, int n_in,
                              void* d_out, int out_size, void* d_ws, size_t ws_size,
                              hipStream_t stream) {
  const float* x      = (const float*)d_in[0];   // [64,64,1,4096] fp32
  const float* params = (const float*)d_in[1];   // [64,64,4] fp32
  const int*   idx    = (const int*)d_in[2];     // [16384] int32
  float* out = (float*)d_out;                    // [64,64,1,16384] fp32

  unsigned short* xt  = (unsigned short*)d_ws;                       // 33.5 MB
  unsigned short* pbf = (unsigned short*)((char*)d_ws + (64u << 20)); // 32 KB @ +64MB

  transpose_bf16<<<dim3(KDIM / 64, NB), 256, 0, stream>>>(x, xt);
  prep_params<<<dim3(64), 256, 0, stream>>>(params, pbf);
  gemm_gather<<<dim3(LDIM / (LT * 16), NB), 256, 0, stream>>>(xt, pbf, idx, out);
}

// Round 3
// 357.420 us; speedup vs baseline: 1.0463x; 1.0463x over previous
//
#include <hip/hip_runtime.h>

// out[b,o,l] = sum_i x[b,i,k'(l)] * P[i,o,f'(l)],  k'=idx[l]&4095, f'=idx[l]>>12
// Phase 1a: xT[b,k,i] = bf16(x[b,i,k])      (coalesced transpose+cast, d_ws)
// Phase 1b: Pbf[f][o][i] = bf16(P[i,o,f])   (A-fragment layout, d_ws)
// Phase 2 : fused gather-GEMM. Gathered 128-B xt rows staged ONCE per block into
//           LDS via global_load_lds width=16 (XOR-swizzled chunks, conflict-free
//           ds_read_b128), double-buffered; K=64, 4 per-f accumulators, cndmask
//           select in the epilogue.

typedef __attribute__((ext_vector_type(8))) short short8;
typedef __attribute__((ext_vector_type(4))) float floatx4;

#define NB    64
#define CIN   64
#define COUT  64
#define KDIM  4096
#define LDIM  16384
#define TILES 8              // 64-l tiles per block -> 512 l per block, grid.x=32

__device__ __forceinline__ unsigned short f2bf(float f) {
  union { float f; unsigned u; } v; v.f = f;
  unsigned r = v.u + 0x7FFFu + ((v.u >> 16) & 1u);  // RNE
  return (unsigned short)(r >> 16);
}

union V16 { uint4 u; short8 s; };

__device__ __forceinline__ void gl2lds16(const void* g, void* l) {
  __builtin_amdgcn_global_load_lds(
      (const __attribute__((address_space(1))) unsigned int*)g,
      (__attribute__((address_space(3))) unsigned int*)l, 16, 0, 0);
}

__global__ __launch_bounds__(256) void transpose_bf16(const float* __restrict__ x,
                                                      unsigned short* __restrict__ xt) {
  __shared__ float tile[64 * 65];  // [i][k], +1 pad
  const int t = threadIdx.x;
  const int b = blockIdx.y;
  const int k0 = blockIdx.x * 64;
  const float4* x4 = (const float4*)x;
#pragma unroll
  for (int p = 0; p < 4; ++p) {
    int i  = p * 16 + (t >> 4);
    int kq = t & 15;
    float4 v = x4[(size_t)(b * CIN + i) * (KDIM / 4) + (k0 >> 2) + kq];
    tile[i * 65 + kq * 4 + 0] = v.x;
    tile[i * 65 + kq * 4 + 1] = v.y;
    tile[i * 65 + kq * 4 + 2] = v.z;
    tile[i * 65 + kq * 4 + 3] = v.w;
  }
  __syncthreads();
  unsigned int* xt32 = (unsigned int*)xt;
  const int ip = (t & 31) * 2;
#pragma unroll
  for (int p = 0; p < 8; ++p) {
    int k = p * 8 + (t >> 5);
    unsigned lo = f2bf(tile[ip * 65 + k]);
    unsigned hi = f2bf(tile[(ip + 1) * 65 + k]);
    xt32[((size_t)b * KDIM + k0 + k) * (CIN / 2) + (ip >> 1)] = lo | (hi << 16);
  }
}

__global__ __launch_bounds__(256) void prep_params(const float* __restrict__ params,
                                                   unsigned short* __restrict__ pbf) {
  const int e = blockIdx.x * 256 + threadIdx.x;
  const int f = e >> 12, o = (e >> 6) & 63, i = e & 63;
  pbf[e] = f2bf(params[(i * COUT + o) * 4 + f]);
}

__global__ __launch_bounds__(256) void gemm_gather(const unsigned short* __restrict__ xt,
                                                   const unsigned short* __restrict__ pbf,
                                                   const int* __restrict__ idx,
                                                   float* __restrict__ out) {
  // double-buffered tile: [buf][l_loc(64)][i(64)] bf16, 8 KB each.
  // chunk c (16B) of row r stored at chunk position c, holding source chunk c^(r&7).
  __shared__ __align__(16) unsigned short lds[2 * 64 * 64];
  const int t = threadIdx.x;
  const int b = blockIdx.y;
  const int w = t >> 6;           // wave id = o-tile
  const int lane = t & 63;
  const int quad = lane >> 4;
  const int lane15 = lane & 15;
  const int o = w * 16 + lane15;

  // A fragments: A[m=o][k=i]; lane m=lane15, k=quad*8+j
  short8 afrag[4][2];
#pragma unroll
  for (int f = 0; f < 4; ++f)
#pragma unroll
    for (int kt = 0; kt < 2; ++kt) {
      V16 v; v.u = *(const uint4*)(pbf + ((f * COUT + o) * CIN + kt * 32 + quad * 8));
      afrag[f][kt] = v.s;
    }

  const int lbase = blockIdx.x * (TILES * 64);
  const unsigned short* xb = xt + (size_t)b * KDIM * CIN;
  const floatx4 zero = {0.f, 0.f, 0.f, 0.f};

  const int subrow = lane >> 3;   // 0..7
  const int chunk  = lane & 7;    // 0..7
  const int swsrc  = chunk ^ (subrow & 7);

  // stage rows [w*16, w*16+16) of tile `it` into buffer bs; ivn = idx[tile it] per lane
#define STAGE(IT, BS, IVN)                                                          \
  {                                                                                 \
    _Pragma("unroll")                                                               \
    for (int j = 0; j < 2; ++j) {                                                   \
      int row = w * 16 + j * 8 + subrow;                                            \
      int iv = __shfl((IVN), row, 64);                                              \
      const char* src = (const char*)xb + (size_t)(iv & (KDIM - 1)) * 128 + (swsrc << 4); \
      gl2lds16(src, (void*)&lds[(BS) * 4096 + (w * 16 + j * 8) * 64]);              \
    }                                                                               \
  }

  int ivv = idx[lbase + lane];         // tile 0
  int ivn = idx[lbase + 64 + lane];    // tile 1
  STAGE(0, 0, ivv);

  for (int it = 0; it < TILES; ++it) {
    __syncthreads();  // staging of tile `it` (and prior stores) drained here
    int iv2 = ivn;
    if (it + 2 < TILES) iv2 = idx[lbase + (it + 2) * 64 + lane];
    if (it + 1 < TILES) STAGE(it + 1, (it + 1) & 1, ivn);

    const unsigned short* B = &lds[(it & 1) * 4096];
#pragma unroll
    for (int nt = 0; nt < 4; ++nt) {
      const int row = nt * 16 + lane15;
      const int sw = lane15 & 7;
      V16 v0, v1;
      v0.u = *(const uint4*)&B[row * 64 + ((quad ^ sw) << 3)];        // chunks 0..3 (kt=0)
      v1.u = *(const uint4*)&B[row * 64 + (((4 + quad) ^ sw) << 3)];  // chunks 4..7 (kt=1)
      floatx4 acc[4];
#pragma unroll
      for (int f = 0; f < 4; ++f) {
        acc[f] = __builtin_amdgcn_mfma_f32_16x16x32_bf16(afrag[f][0], v0.s, zero, 0, 0, 0);
        acc[f] = __builtin_amdgcn_mfma_f32_16x16x32_bf16(afrag[f][1], v1.s, acc[f], 0, 0, 0);
      }
      const int fsel = __shfl(ivv, nt * 16 + lane15, 64) >> 12;
      const int l = lbase + it * 64 + nt * 16 + lane15;
#pragma unroll
      for (int r = 0; r < 4; ++r) {
        float v01 = (fsel == 0) ? acc[0][r] : acc[1][r];
        float v23 = (fsel == 2) ? acc[2][r] : acc[3][r];
        float v = (fsel < 2) ? v01 : v23;
        out[((size_t)(b * COUT + w * 16 + quad * 4 + r)) * LDIM + l] = v;
      }
    }
    ivv = ivn;
    ivn = iv2;
  }
#undef STAGE
}

extern "C" void kernel_launch(void* const* d_in, const int* in_sizes, int n_in,
                              void* d_out, int out_size, void* d_ws, size_t ws_size,
                              hipStream_t stream) {
  const float* x      = (const float*)d_in[0];   // [64,64,1,4096] fp32
  const float* params = (const float*)d_in[1];   // [64,64,4] fp32
  const int*   idx    = (const int*)d_in[2];     // [16384] int32
  float* out = (float*)d_out;                    // [64,64,1,16384] fp32

  unsigned short* xt  = (unsigned short*)d_ws;                        // 33.5 MB
  unsigned short* pbf = (unsigned short*)((char*)d_ws + (64u << 20)); // 32 KB @ +64MB

  transpose_bf16<<<dim3(KDIM / 64, NB), 256, 0, stream>>>(x, xt);
  prep_params<<<dim3(64), 256, 0, stream>>>(params, pbf);
  gemm_gather<<<dim3(LDIM / (TILES * 64), NB), 256, 0, stream>>>(xt, pbf, idx, out);
}